// Round 10
// baseline (426.074 us; speedup 1.0000x reference)
//
#include <hip/hip_runtime.h>
#include <hip/hip_fp16.h>

#define FIN 128
#define HD 128
#define COUT 16

#define SLOT_CAP 48          // max in-degree safety cap (actual max ~40)
#define CS_BLOCKS 512        // coarse-scatter blocks
#define CB_SHIFT 9           // 512-node coarse buckets
#define CB_SIZE 512
#define CAP_B 10240          // fixed bucket capacity (mean 8192, +22 sigma)
#define GMK_CELLS 64         // spread atomicMax over 64 cells, 64-B stride
#define NBINS 49             // degree bins 0..SLOT_CAP
#define SBUF_CAP 3136        // LDS staging items per scatter tile (>= chunk 3125)
#define DONE_SLOT 50         // hist[] cell used as fine-block done counter

typedef _Float16 half8 __attribute__((ext_vector_type(8)));
typedef float floatx4 __attribute__((ext_vector_type(4)));

// ---------- helpers ----------
__device__ __forceinline__ float lrelu02(float x) { return x > 0.f ? x : 0.2f * x; }

union U4H8 { uint4 q; __half2 h2[4]; };
union UQH8 { uint4 q; half8 h; _Float16 e[8]; };

__device__ __forceinline__ void h8f(const uint4 q, float* f) {
    U4H8 u; u.q = q;
    float2 a0 = __half22float2(u.h2[0]);
    float2 a1 = __half22float2(u.h2[1]);
    float2 a2 = __half22float2(u.h2[2]);
    float2 a3 = __half22float2(u.h2[3]);
    f[0] = a0.x; f[1] = a0.y; f[2] = a1.x; f[3] = a1.y;
    f[4] = a2.x; f[5] = a2.y; f[6] = a3.x; f[7] = a3.y;
}

// monotone float->uint key for atomicMax over floats (handles negatives)
__device__ __forceinline__ unsigned fkey(float f) {
    unsigned u = __float_as_uint(f);
    return (u & 0x80000000u) ? ~u : (u | 0x80000000u);
}
__device__ __forceinline__ float funkey(unsigned k) {
    return (k & 0x80000000u) ? __uint_as_float(k ^ 0x80000000u)
                             : __uint_as_float(~k);
}

// ---------- setup: W swizzles (blocks 0..23) + zero cursors/hist (block 24) ----------
__global__ void k_setup(const float* __restrict__ W1, const float* __restrict__ W2,
                        const float* __restrict__ Wg, __half* __restrict__ w1z,
                        __half* __restrict__ w2z, __half* __restrict__ wgz,
                        int* __restrict__ cur, unsigned* __restrict__ gmk,
                        int* __restrict__ hist) {
    int b = blockIdx.x;
    if (b < 24) {
        const float* W = (b < 8) ? W1 : (b < 16) ? W2 : Wg;
        __half* outp   = (b < 8) ? w1z : (b < 16) ? w2z : wgz;
        int t = (b & 7) * 256 + threadIdx.x;   // 0..2047
        int lane = t & 63;
        int kc = (t >> 6) & 3;
        int nt = t >> 8;
        int kbase = kc * 32 + (lane >> 4) * 8;
        int col = nt * 16 + (lane & 15);
        UQH8 u;
#pragma unroll
        for (int j = 0; j < 8; j++)
            u.e[j] = (_Float16)W[(kbase + j) * 128 + col];
        ((uint4*)outp)[t] = u.q;
    } else {
        cur[threadIdx.x] = 0;
        if (threadIdx.x < 64) hist[threadIdx.x] = 0;   // includes DONE_SLOT
        for (int i = threadIdx.x; i < GMK_CELLS * 16; i += 256)
            gmk[i] = 0u;   // key 0 == -inf sentinel
    }
}

// ---------- MFMA GEMM body: [M,128] @ [128,128] -> fp16 (global A) ----------
// A-frag: A[m=lane&15][k=(lane>>4)*8+j]; C/D: col=lane&15, row=(lane>>4)*4+reg.
// Generic over wave id and row base; per-row store guard.
__device__ __forceinline__
void gemm_rows16(int m0, const float* __restrict__ A, const __half* __restrict__ Wz,
                 __half* __restrict__ Out, int lane, int n) {
    if (m0 >= n) return;
    int m = lane & 15;
    int quad = lane >> 4;

    half8 a[4];
#pragma unroll
    for (int kc = 0; kc < 4; kc++) {
        const float* p = &A[(size_t)(m0 + m) * 128 + kc * 32 + quad * 8];
        float4 f0 = *(const float4*)p;
        float4 f1 = *(const float4*)(p + 4);
        UQH8 u;
        u.e[0] = (_Float16)f0.x; u.e[1] = (_Float16)f0.y;
        u.e[2] = (_Float16)f0.z; u.e[3] = (_Float16)f0.w;
        u.e[4] = (_Float16)f1.x; u.e[5] = (_Float16)f1.y;
        u.e[6] = (_Float16)f1.z; u.e[7] = (_Float16)f1.w;
        a[kc] = u.h;
    }

    floatx4 acc[8];
#pragma unroll
    for (int nt = 0; nt < 8; nt++) acc[nt] = (floatx4){0.f, 0.f, 0.f, 0.f};

    const uint4* Wv = (const uint4*)Wz;
#pragma unroll
    for (int kc = 0; kc < 4; kc++) {
#pragma unroll
        for (int nt = 0; nt < 8; nt++) {
            UQH8 u;
            u.q = Wv[(nt * 4 + kc) * 64 + lane];
            acc[nt] = __builtin_amdgcn_mfma_f32_16x16x32_f16(a[kc], u.h, acc[nt], 0, 0, 0);
        }
    }
#pragma unroll
    for (int reg = 0; reg < 4; reg++) {
        int row = m0 + quad * 4 + reg;
        if (row < n) {
#pragma unroll
            for (int nt = 0; nt < 8; nt++)
                Out[(size_t)row * 128 + nt * 16 + m] = __float2half(acc[nt][reg]);
        }
    }
}

// NOTE: caller guards m0 range. Reads A rows m0+(lane&15): requires m0+15 < n
// or row-guarded stores; A reads of rows >= n would be OOB, so callers must
// ensure m0+15 <= n-1 OR m0 >= n (handled: k_csc_gemm uses multiples of 64
// with nGemm <= n; k_fine filler guards m0+15 < n before calling, tail rows
// handled by the 256-thread gather-GEMM path writes... tail covered below).

// ---------- coarse scatter via LDS counting sort (blocks < CS_BLOCKS) + GEMM1-A ----------
// Stage chunk in LDS, sort by bucket, reserve one run per bucket with a single
// global atomic, write each run contiguously (avg 128-B bursts).
// item: .x = (dstLocal<<17) | src  (9+17 bits), .y = bit-cast ew
__launch_bounds__(256)
__global__ void k_csc_gemm(const int* __restrict__ src, const int* __restrict__ dst,
                           const float* __restrict__ ew, int* __restrict__ cur,
                           int2* __restrict__ coarseBuf, int e,
                           const float* __restrict__ x, const __half* __restrict__ w1z,
                           __half* __restrict__ buf0, int nGemm) {
    __shared__ int2 sbuf[SBUF_CAP];
    __shared__ unsigned short sbufb[SBUF_CAP];
    __shared__ int lcnt[256], lofs[256], lpos[256], lbase[256];
    if ((int)blockIdx.x < CS_BLOCKS) {
        int tid = threadIdx.x;
        int chunk = (e + CS_BLOCKS - 1) / CS_BLOCKS;
        int s0 = blockIdx.x * chunk;
        int s1 = min(s0 + chunk, e);
        for (int t0 = s0; t0 < s1; t0 += SBUF_CAP) {
            int t1 = min(t0 + SBUF_CAP, s1);
            lcnt[tid] = 0; lpos[tid] = 0;
            __syncthreads();
            // pass 1: bucket histogram
            for (int i = t0 + tid; i < t1; i += 256)
                atomicAdd(&lcnt[dst[i] >> CB_SHIFT], 1);
            __syncthreads();
            // inclusive Hillis-Steele scan of lcnt -> lofs
            lofs[tid] = lcnt[tid];
            __syncthreads();
            for (int d = 1; d < 256; d <<= 1) {
                int v = (tid >= d) ? lofs[tid - d] : 0;
                __syncthreads();
                lofs[tid] += v;
                __syncthreads();
            }
            // reserve global runs (one atomic per non-empty bucket)
            if (lcnt[tid] > 0) lbase[tid] = atomicAdd(&cur[tid], lcnt[tid]);
            __syncthreads();
            // pass 2: place items into LDS, bucket-sorted
            for (int i = t0 + tid; i < t1; i += 256) {
                int d = dst[i];
                int b = d >> CB_SHIFT;
                int p = (lofs[b] - lcnt[b]) + atomicAdd(&lpos[b], 1);
                sbuf[p] = make_int2(((d & (CB_SIZE - 1)) << 17) | src[i],
                                    __float_as_int(ew[i]));
                sbufb[p] = (unsigned short)b;
            }
            __syncthreads();
            // pass 3: contiguous run write-out (coalesced within runs)
            int total = t1 - t0;
            for (int t = tid; t < total; t += 256) {
                int b = sbufb[t];
                int local = t - (lofs[b] - lcnt[b]);
                int gpos = lbase[b] + local;
                if (gpos < CAP_B)
                    coarseBuf[(size_t)b * CAP_B + gpos] = sbuf[t];
            }
            __syncthreads();
        }
    } else {
        int blk = blockIdx.x - CS_BLOCKS;
        int wave = threadIdx.x >> 6;
        int lane = threadIdx.x & 63;
        gemm_rows16(blk * 64 + wave * 16, x, w1z, buf0, lane, nGemm);
    }
}

// ---------- fine fill (blocks < NB) + GEMM1-B filler (blocks >= NB) ----------
// Fine blocks: one 512-thread block per bucket; last-finishing block computes
// the degree-bin prefix (binCur) so no separate k_prefix launch is needed.
// Filler blocks: 8 waves x 16 rows = 128 GEMM rows each, covering [RA, n).
__launch_bounds__(512)
__global__ void k_fine(const int2* __restrict__ coarseBuf, const int* __restrict__ cur,
                       int2* __restrict__ slots, int* __restrict__ cnt,
                       float* __restrict__ dinv, int* __restrict__ hist,
                       int* __restrict__ binCur, int NBv, int RA, int n,
                       const float* __restrict__ x, const __half* __restrict__ w1z,
                       __half* __restrict__ buf0) {
    __shared__ int lcnt[CB_SIZE];
    __shared__ float lsum[CB_SIZE];
    __shared__ int lhist[NBINS];
    if ((int)blockIdx.x >= NBv) {
        // GEMM1-B filler: rows RA + fb*128 + wave*16
        int fb = blockIdx.x - NBv;
        int wave = threadIdx.x >> 6;     // 0..7
        int lane = threadIdx.x & 63;
        int m0 = RA + fb * 128 + wave * 16;
        if (m0 + 15 < n) {
            gemm_rows16(m0, x, w1z, buf0, lane, n);
        } else if (m0 < n) {
            // tail: rows m0..n-1 (A-row reads must stay in-bounds) — scalar path
            int m = lane & 15;
            if (m0 + m < n) {
                // gather A row safely then do the same MFMA shape with guards:
                // simplest correct tail: compute row-by-row dot via VALU
                // (≤15 rows once per launch; cost negligible)
                for (int row = m0; row < n; row++) {
                    // 512 threads cooperate: thread t handles col t%128, rows split
                    int col = threadIdx.x & 127;
                    int half_ = threadIdx.x >> 7;   // 0..3 → 4-way split over k
                    if (row % 4 != half_ && false) {}
                    if ((threadIdx.x >> 7) == (row & 3)) {
                        float acc = 0.f;
                        for (int k = 0; k < 128; k++) {
                            // w1z swizzled: W[k][col] at swizzle layout — recompute:
                            // layout: ((uint4*)w1z)[t2] with t2 = nt*256+kc*64+lane2
                            // element j of that uint4 = W[kc*32+(lane2>>4)*8+j][nt*16+(lane2&15)]
                            int nt = col >> 4, c16 = col & 15;
                            int kc = k >> 5, kr = k & 31;
                            int lane2 = (kr >> 3) * 16 + c16;
                            int j = kr & 7;
                            const __half* wp = w1z + ((size_t)(nt * 4 + kc) * 64 + lane2) * 8 + j;
                            acc += x[(size_t)row * 128 + k] * __half2float(*wp);
                        }
                        buf0[(size_t)row * 128 + col] = __float2half(acc);
                    }
                }
            }
        }
        return;
    }
    int b = blockIdx.x;
    int tid = threadIdx.x;
    if (tid < CB_SIZE) { lcnt[tid] = 0; lsum[tid] = 0.f; }
    if (tid < NBINS) lhist[tid] = 0;
    __syncthreads();
    int ecnt = min(cur[b], CAP_B);
    size_t e0 = (size_t)b * CAP_B;
    for (int e = tid; e < ecnt; e += 512) {
        int2 it = coarseBuf[e0 + e];
        int dl = (it.x >> 17) & (CB_SIZE - 1);
        int srcn = it.x & 0x1FFFF;
        int pos = atomicAdd(&lcnt[dl], 1);
        atomicAdd(&lsum[dl], __int_as_float(it.y));
        if (pos < SLOT_CAP) {
            int node = (b << CB_SHIFT) + dl;
            slots[(size_t)node * SLOT_CAP + pos] = make_int2(srcn, it.y);
        }
    }
    __syncthreads();
    if (tid < CB_SIZE) {
        int node = (b << CB_SHIFT) + tid;
        if (node < n) {
            int c = min(lcnt[tid], SLOT_CAP);
            cnt[node] = c;
            dinv[node] = rsqrtf(1.0f + lsum[tid]);
            atomicAdd(&lhist[c], 1);
        }
    }
    __syncthreads();
    if (tid < NBINS && lhist[tid] > 0) atomicAdd(&hist[tid], lhist[tid]);
    __syncthreads();
    if (tid == 0) {
        __threadfence();
        if (atomicAdd(&hist[DONE_SLOT], 1) == NBv - 1) {
            // last fine block: 49-bin exclusive prefix into binCur
            int acc = 0;
            for (int c2 = 0; c2 < NBINS; c2++) {
                int h = atomicAdd(&hist[c2], 0);   // L2-coherent read
                binCur[c2] = acc;
                acc += h;
            }
        }
    }
}

// ---------- permutation scatter: perm sorted by degree (counting sort) ----------
__launch_bounds__(512)
__global__ void k_permscatter(const int* __restrict__ cnt, int* __restrict__ binCur,
                              int* __restrict__ perm, int n) {
    __shared__ int lh[NBINS], lb[NBINS], lp[NBINS];
    int tid = threadIdx.x;
    if (tid < NBINS) { lh[tid] = 0; lp[tid] = 0; }
    __syncthreads();
    int node = blockIdx.x * 512 + tid;
    int c = -1;
    if (node < n) { c = cnt[node]; atomicAdd(&lh[c], 1); }
    __syncthreads();
    if (tid < NBINS && lh[tid] > 0) lb[tid] = atomicAdd(&binCur[tid], lh[tid]);
    __syncthreads();
    if (node < n) {
        int pos = lb[c] + atomicAdd(&lp[c], 1);
        perm[pos] = node;
    }
}

// ---------- GCN gather body: 16 lanes/node, inline weight dinv[s]*ew*dd ----------
__device__ __forceinline__
void gather_body(int node, int lane, const int* __restrict__ cnt,
                 const int2* __restrict__ slots, const uint4* __restrict__ tv,
                 const float* __restrict__ dinv, const float* __restrict__ b,
                 float* __restrict__ fout) {
    float dd = dinv[node];
    float sw = dd * dd;
    float acc[8];
    {
        uint4 q = tv[(size_t)node * 16 + lane];
        float f[8]; h8f(q, f);
#pragma unroll
        for (int j = 0; j < 8; j++) acc[j] = f[j] * sw;
    }
    int r0 = (int)((size_t)node * SLOT_CAP);
    int r1 = r0 + cnt[node];
    int e = r0;
    for (; e + 8 <= r1; e += 8) {
        int2 c[8];
        float dv[8];
        uint4 v[8];
#pragma unroll
        for (int j = 0; j < 8; j++) c[j] = slots[e + j];
#pragma unroll
        for (int j = 0; j < 8; j++) dv[j] = dinv[c[j].x];
#pragma unroll
        for (int j = 0; j < 8; j++) v[j] = tv[(size_t)c[j].x * 16 + lane];
#pragma unroll
        for (int j = 0; j < 8; j++) {
            float w = dv[j] * __int_as_float(c[j].y) * dd;
            float f[8]; h8f(v[j], f);
#pragma unroll
            for (int k = 0; k < 8; k++) acc[k] = fmaf(f[k], w, acc[k]);
        }
    }
    for (; e + 2 <= r1; e += 2) {
        int2 c0 = slots[e], c1 = slots[e + 1];
        float dv0 = dinv[c0.x], dv1 = dinv[c1.x];
        uint4 v0 = tv[(size_t)c0.x * 16 + lane];
        uint4 v1 = tv[(size_t)c1.x * 16 + lane];
        float w0 = dv0 * __int_as_float(c0.y) * dd;
        float w1 = dv1 * __int_as_float(c1.y) * dd;
        float f0[8], f1[8]; h8f(v0, f0); h8f(v1, f1);
#pragma unroll
        for (int k = 0; k < 8; k++) acc[k] = fmaf(f0[k], w0, acc[k]);
#pragma unroll
        for (int k = 0; k < 8; k++) acc[k] = fmaf(f1[k], w1, acc[k]);
    }
    if (e < r1) {
        int2 c = slots[e];
        uint4 v = tv[(size_t)c.x * 16 + lane];
        float w = dinv[c.x] * __int_as_float(c.y) * dd;
        float f[8]; h8f(v, f);
#pragma unroll
        for (int k = 0; k < 8; k++) acc[k] = fmaf(f[k], w, acc[k]);
    }
    const float4* b4 = (const float4*)b;
    float4 bb0 = b4[lane * 2], bb1 = b4[lane * 2 + 1];
    fout[0] = fmaxf(acc[0] + bb0.x, 0.f);
    fout[1] = fmaxf(acc[1] + bb0.y, 0.f);
    fout[2] = fmaxf(acc[2] + bb0.z, 0.f);
    fout[3] = fmaxf(acc[3] + bb0.w, 0.f);
    fout[4] = fmaxf(acc[4] + bb1.x, 0.f);
    fout[5] = fmaxf(acc[5] + bb1.y, 0.f);
    fout[6] = fmaxf(acc[6] + bb1.z, 0.f);
    fout[7] = fmaxf(acc[7] + bb1.w, 0.f);
}

// ---------- fused GCN gather + MFMA GEMM (+ optional attn epilogue) ----------
// Block = 16 PERMUTED nodes (degree-sorted: near-equal trip counts per wave).
template <bool ATTN>
__launch_bounds__(256)
__global__ void k_gather_gemm(const int* __restrict__ cnt, const int2* __restrict__ slots,
                              const __half* __restrict__ t, const float* __restrict__ dinv,
                              const float* __restrict__ b, const __half* __restrict__ Wz,
                              __half* __restrict__ Out, const int* __restrict__ perm,
                              const float* __restrict__ attS, const float* __restrict__ attD,
                              float* __restrict__ as_, float* __restrict__ ad_,
                              unsigned* __restrict__ gmaxKey, int n) {
    __shared__ __half stage[16][136];      // 272-B row stride: <=2-way LDS aliasing
    __shared__ float redS[4][16], redD[4][16];
    int tid = threadIdx.x;
    int nl = tid >> 4;
    int lane16 = tid & 15;
    int idx16 = blockIdx.x * 16 + nl;
    int node = (idx16 < n) ? perm[idx16] : -1;

    if (node >= 0) {
        float f[8];
        gather_body(node, lane16, cnt, slots, (const uint4*)t, dinv, b, f);
        UQH8 u;
#pragma unroll
        for (int j = 0; j < 8; j++) u.e[j] = (_Float16)f[j];
        *(uint4*)&stage[nl][lane16 * 8] = u.q;
    } else {
        UQH8 u;
#pragma unroll
        for (int j = 0; j < 8; j++) u.e[j] = (_Float16)0.f;
        *(uint4*)&stage[nl][lane16 * 8] = u.q;
    }
    __syncthreads();

    int wave = tid >> 6;
    int lane = tid & 63;
    int m = lane & 15;
    int quad = lane >> 4;
    int m0 = blockIdx.x * 16;

    half8 a[4];
#pragma unroll
    for (int kc = 0; kc < 4; kc++)
        a[kc] = *(const half8*)&stage[m][kc * 32 + quad * 8];

    floatx4 acc[2];
    acc[0] = (floatx4){0.f, 0.f, 0.f, 0.f};
    acc[1] = (floatx4){0.f, 0.f, 0.f, 0.f};
    const uint4* Wv = (const uint4*)Wz;
#pragma unroll
    for (int t2 = 0; t2 < 2; t2++) {
        int nt = wave * 2 + t2;
#pragma unroll
        for (int kc = 0; kc < 4; kc++) {
            UQH8 u;
            u.q = Wv[(nt * 4 + kc) * 64 + lane];
            acc[t2] = __builtin_amdgcn_mfma_f32_16x16x32_f16(a[kc], u.h, acc[t2], 0, 0, 0);
        }
    }
#pragma unroll
    for (int reg = 0; reg < 4; reg++) {
        int row = m0 + quad * 4 + reg;
        if (row < n) {
            int prow = perm[row];
#pragma unroll
            for (int t2 = 0; t2 < 2; t2++) {
                int col = (wave * 2 + t2) * 16 + m;
                Out[(size_t)prow * 128 + col] = __float2half(acc[t2][reg]);
            }
        }
    }

    if (ATTN) {
        float sv0 = attS[(wave * 2 + 0) * 16 + m], sv1 = attS[(wave * 2 + 1) * 16 + m];
        float dv0 = attD[(wave * 2 + 0) * 16 + m], dv1 = attD[(wave * 2 + 1) * 16 + m];
#pragma unroll
        for (int reg = 0; reg < 4; reg++) {
            float s = acc[0][reg] * sv0 + acc[1][reg] * sv1;
            float d = acc[0][reg] * dv0 + acc[1][reg] * dv1;
#pragma unroll
            for (int k = 8; k >= 1; k >>= 1) {
                s += __shfl_xor(s, k, 64);   // xor bits <16: stays in quad's 16-group
                d += __shfl_xor(d, k, 64);
            }
            if (m == 0) {
                redS[wave][quad * 4 + reg] = s;
                redD[wave][quad * 4 + reg] = d;
            }
        }
        __syncthreads();
        if (tid < 16) {
            int nd = m0 + tid;
            unsigned key = 0u;
            if (nd < n) {
                float sv = redS[0][tid] + redS[1][tid] + redS[2][tid] + redS[3][tid];
                float dv = redD[0][tid] + redD[1][tid] + redD[2][tid] + redD[3][tid];
                int pn = perm[nd];
                as_[pn] = sv;
                ad_[pn] = dv;
                key = fkey(sv);
            }
            // max of the 16 keys (xor bits <16 keep lanes 0..15 within group)
#pragma unroll
            for (int k = 8; k >= 1; k >>= 1) {
                unsigned o = (unsigned)__shfl_xor((int)key, k, 64);
                key = key > o ? key : o;
            }
            if (tid == 0)
                atomicMax(&gmaxKey[(blockIdx.x & (GMK_CELLS - 1)) << 4], key);
        }
    }
}

// ---------- GAT gather + fused final projection (perm-ordered blocks) ----------
__launch_bounds__(256)
__global__ void k_gat_final(const int* __restrict__ cnt, const int2* __restrict__ slots,
                            const __half* __restrict__ g, const float* __restrict__ as_,
                            const float* __restrict__ ad_,
                            const unsigned* __restrict__ gmaxKey,
                            const int* __restrict__ perm,
                            const float* __restrict__ bg,
                            const float* __restrict__ Wc, const float* __restrict__ bc,
                            float* __restrict__ out, int n) {
    __shared__ float Wcs[128 * 16];
    __shared__ float bcs[16];
    __shared__ float stage[16][136];
    __shared__ float gmaxS;
    int tid = threadIdx.x;
    for (int i = tid; i < 128 * 16; i += 256) Wcs[i] = Wc[i];
    if (tid < 16) bcs[tid] = bc[tid];

    // reduce the 64 spread max-cells (first wave), broadcast via LDS
    if (tid < 64) {
        unsigned k = gmaxKey[tid << 4];
#pragma unroll
        for (int d = 32; d >= 1; d >>= 1) {
            unsigned o = (unsigned)__shfl_xor((int)k, d, 64);
            k = k > o ? k : o;
        }
        if (tid == 0) gmaxS = funkey(k);
    }
    __syncthreads();
    float gmax = gmaxS;

    int idx = blockIdx.x * 256 + tid;
    int lidx = idx >> 4;
    int node = (lidx < n) ? perm[lidx] : -1;
    int lane = idx & 15;
    int nl = tid >> 4;

    if (node >= 0) {
        int r0 = (int)((size_t)node * SLOT_CAP);
        int r1 = r0 + cnt[node];
        float ad_d = ad_[node];
        float c = lrelu02(gmax + ad_d);          // upper bound of all logits
        const uint4* gv = (const uint4*)g;
        float ex = __expf(lrelu02(as_[node] + ad_d) - c);
        float den = ex;
        float acc[8];
        {
            uint4 q = gv[(size_t)node * 16 + lane];
            float f[8]; h8f(q, f);
#pragma unroll
            for (int j = 0; j < 8; j++) acc[j] = ex * f[j];
        }
        int e = r0;
        for (; e + 8 <= r1; e += 8) {
            int s[8];
            float av[8];
            uint4 u[8];
#pragma unroll
            for (int j = 0; j < 8; j++) s[j] = slots[e + j].x;
#pragma unroll
            for (int j = 0; j < 8; j++) av[j] = as_[s[j]];
#pragma unroll
            for (int j = 0; j < 8; j++) u[j] = gv[(size_t)s[j] * 16 + lane];
#pragma unroll
            for (int j = 0; j < 8; j++) {
                float w = __expf(lrelu02(av[j] + ad_d) - c);
                den += w;
                float f[8]; h8f(u[j], f);
#pragma unroll
                for (int k = 0; k < 8; k++) acc[k] = fmaf(f[k], w, acc[k]);
            }
        }
        for (; e + 2 <= r1; e += 2) {
            int s0 = slots[e].x, s1 = slots[e + 1].x;
            uint4 u0 = gv[(size_t)s0 * 16 + lane];
            uint4 u1 = gv[(size_t)s1 * 16 + lane];
            float w0 = __expf(lrelu02(as_[s0] + ad_d) - c);
            float w1 = __expf(lrelu02(as_[s1] + ad_d) - c);
            den += w0 + w1;
            float f0[8], f1[8]; h8f(u0, f0); h8f(u1, f1);
#pragma unroll
            for (int k = 0; k < 8; k++) acc[k] = fmaf(f0[k], w0, acc[k]);
#pragma unroll
            for (int k = 0; k < 8; k++) acc[k] = fmaf(f1[k], w1, acc[k]);
        }
        if (e < r1) {
            int s = slots[e].x;
            uint4 u = gv[(size_t)s * 16 + lane];
            float w = __expf(lrelu02(as_[s] + ad_d) - c);
            den += w;
            float f[8]; h8f(u, f);
#pragma unroll
            for (int k = 0; k < 8; k++) acc[k] = fmaf(f[k], w, acc[k]);
        }
        float inv = 1.0f / den;
        const float4* bg4 = (const float4*)bg;
        float4 b0 = bg4[lane * 2], b1 = bg4[lane * 2 + 1];
        float* sp = &stage[nl][lane * 8];
        sp[0] = fmaxf(acc[0] * inv + b0.x, 0.f);
        sp[1] = fmaxf(acc[1] * inv + b0.y, 0.f);
        sp[2] = fmaxf(acc[2] * inv + b0.z, 0.f);
        sp[3] = fmaxf(acc[3] * inv + b0.w, 0.f);
        sp[4] = fmaxf(acc[4] * inv + b1.x, 0.f);
        sp[5] = fmaxf(acc[5] * inv + b1.y, 0.f);
        sp[6] = fmaxf(acc[6] * inv + b1.z, 0.f);
        sp[7] = fmaxf(acc[7] * inv + b1.w, 0.f);
    }
    __syncthreads();
    int nl2 = tid >> 4;
    int col = tid & 15;
    int oidx = blockIdx.x * 16 + nl2;
    if (oidx >= n) return;
    int onode = perm[oidx];
    float accp = bcs[col];
    const float* sp = stage[nl2];
#pragma unroll 8
    for (int k = 0; k < 128; k++)
        accp = fmaf(sp[k], Wcs[k * 16 + col], accp);
    out[(size_t)onode * 16 + col] = accp;
}

// ---------- launch ----------
extern "C" void kernel_launch(void* const* d_in, const int* in_sizes, int n_in,
                              void* d_out, int out_size, void* d_ws, size_t ws_size,
                              hipStream_t stream) {
    const float* x      = (const float*)d_in[0];
    const int*   eidx   = (const int*)d_in[1];
    const float* ew     = (const float*)d_in[2];
    const float* W1     = (const float*)d_in[3];
    const float* b1     = (const float*)d_in[4];
    const float* W2     = (const float*)d_in[5];
    const float* b2     = (const float*)d_in[6];
    const float* Wg     = (const float*)d_in[7];
    const float* attS   = (const float*)d_in[8];
    const float* attD   = (const float*)d_in[9];
    const float* bg     = (const float*)d_in[10];
    const float* Wc     = (const float*)d_in[11];
    const float* bc     = (const float*)d_in[12];

    const int N = in_sizes[0] / FIN;   // 100000
    const int E = in_sizes[2];         // 1600000
    const int* src = eidx;
    const int* dst = eidx + E;
    const int NB = (N + CB_SIZE - 1) >> CB_SHIFT;   // 196 buckets (<= 256)

    // GEMM1 row split: RA rows fused with the scatter (soak), rest fused with
    // the fine fill (fills the >50% idle CUs during the 196-block fill phase).
    int RA = (N * 2 / 5) & ~63;          // ~40% of rows, multiple of 64
    if (RA > N) RA = N & ~63;
    int gemmGridA = RA / 64;
    int fineGemmGrid = (N > RA) ? (N - RA + 127) / 128 : 0;

    // 256-B aligned workspace carve (16-B misalignment = +50% gather traffic).
    char* base = (char*)d_ws;
    size_t off = 0;
    auto carve = [&](size_t bytes) {
        char* q = base + off;
        off = (off + bytes + 255) & ~(size_t)255;
        return (void*)q;
    };
    int*    cnt       = (int*)carve((size_t)N * 4);
    int*    cur       = (int*)carve(256 * 4);
    unsigned* gmk     = (unsigned*)carve((size_t)GMK_CELLS * 16 * 4);
    int*    hist      = (int*)carve(64 * 4);
    int*    binCur    = (int*)carve(64 * 4);
    int*    perm      = (int*)carve((size_t)N * 4);
    int2*   coarseBuf = (int2*)carve((size_t)NB * CAP_B * 8);
    int2*   slots     = (int2*)carve((size_t)N * SLOT_CAP * 8);
    float*  dinv      = (float*)carve((size_t)N * 4);
    float*  as_       = (float*)carve((size_t)N * 4);
    float*  ad_       = (float*)carve((size_t)N * 4);
    __half* w1z       = (__half*)carve((size_t)128 * 128 * 2);
    __half* w2z       = (__half*)carve((size_t)128 * 128 * 2);
    __half* wgz       = (__half*)carve((size_t)128 * 128 * 2);
    __half* buf0      = (__half*)carve((size_t)N * 128 * 2);
    __half* buf1      = (__half*)carve((size_t)N * 128 * 2);

    const int B = 256;
    dim3 blk(B);
    int fusedGrid = (N + 15) / 16;       // 16 nodes per block

    k_setup<<<25, blk, 0, stream>>>(W1, W2, Wg, w1z, w2z, wgz, cur, gmk, hist);
    k_csc_gemm<<<CS_BLOCKS + gemmGridA, blk, 0, stream>>>(src, dst, ew, cur, coarseBuf, E,
                                                          x, w1z, buf0, RA);
    k_fine<<<NB + fineGemmGrid, dim3(512), 0, stream>>>(coarseBuf, cur, slots, cnt,
                                                        dinv, hist, binCur, NB, RA, N,
                                                        x, w1z, buf0);
    k_permscatter<<<NB, dim3(512), 0, stream>>>(cnt, binCur, perm, N);

    k_gather_gemm<false><<<fusedGrid, blk, 0, stream>>>(cnt, slots, buf0, dinv, b1, w2z,
                                                        buf1, perm, nullptr, nullptr,
                                                        nullptr, nullptr, nullptr, N);
    k_gather_gemm<true><<<fusedGrid, blk, 0, stream>>>(cnt, slots, buf1, dinv, b2, wgz,
                                                       buf0, perm, attS, attD, as_, ad_,
                                                       gmk, N);
    k_gat_final<<<fusedGrid, blk, 0, stream>>>(cnt, slots, buf0, as_, ad_, gmk, perm, bg,
                                               Wc, bc, (float*)d_out, N);
}

// Round 11
// 405.718 us; speedup vs baseline: 1.0502x; 1.0502x over previous
//
#include <hip/hip_runtime.h>
#include <hip/hip_fp16.h>

#define FIN 128
#define HD 128
#define COUT 16

#define SLOT_CAP 48          // max in-degree safety cap (actual max ~40)
#define CS_BLOCKS 512        // coarse-scatter blocks
#define CB_SHIFT 9           // 512-node coarse buckets
#define CB_SIZE 512
#define CAP_B 10240          // fixed bucket capacity (mean 8192, +22 sigma)
#define GMK_CELLS 64         // spread atomicMax over 64 cells, 64-B stride
#define NBINS 49             // degree bins 0..SLOT_CAP
#define SBUF_CAP 3136        // LDS staging items per scatter tile (>= chunk 3125)

typedef _Float16 half8 __attribute__((ext_vector_type(8)));
typedef float floatx4 __attribute__((ext_vector_type(4)));

// ---------- helpers ----------
__device__ __forceinline__ float lrelu02(float x) { return x > 0.f ? x : 0.2f * x; }

union U4H8 { uint4 q; __half2 h2[4]; };
union UQH8 { uint4 q; half8 h; _Float16 e[8]; };

__device__ __forceinline__ void h8f(const uint4 q, float* f) {
    U4H8 u; u.q = q;
    float2 a0 = __half22float2(u.h2[0]);
    float2 a1 = __half22float2(u.h2[1]);
    float2 a2 = __half22float2(u.h2[2]);
    float2 a3 = __half22float2(u.h2[3]);
    f[0] = a0.x; f[1] = a0.y; f[2] = a1.x; f[3] = a1.y;
    f[4] = a2.x; f[5] = a2.y; f[6] = a3.x; f[7] = a3.y;
}

// monotone float->uint key for atomicMax over floats (handles negatives)
__device__ __forceinline__ unsigned fkey(float f) {
    unsigned u = __float_as_uint(f);
    return (u & 0x80000000u) ? ~u : (u | 0x80000000u);
}
__device__ __forceinline__ float funkey(unsigned k) {
    return (k & 0x80000000u) ? __uint_as_float(k ^ 0x80000000u)
                             : __uint_as_float(~k);
}

// ---------- setup: W swizzles (blocks 0..23) + zero cursors/hist (block 24) ----------
__global__ void k_setup(const float* __restrict__ W1, const float* __restrict__ W2,
                        const float* __restrict__ Wg, __half* __restrict__ w1z,
                        __half* __restrict__ w2z, __half* __restrict__ wgz,
                        int* __restrict__ cur, unsigned* __restrict__ gmk,
                        int* __restrict__ hist) {
    int b = blockIdx.x;
    if (b < 24) {
        const float* W = (b < 8) ? W1 : (b < 16) ? W2 : Wg;
        __half* outp   = (b < 8) ? w1z : (b < 16) ? w2z : wgz;
        int t = (b & 7) * 256 + threadIdx.x;   // 0..2047
        int lane = t & 63;
        int kc = (t >> 6) & 3;
        int nt = t >> 8;
        int kbase = kc * 32 + (lane >> 4) * 8;
        int col = nt * 16 + (lane & 15);
        UQH8 u;
#pragma unroll
        for (int j = 0; j < 8; j++)
            u.e[j] = (_Float16)W[(kbase + j) * 128 + col];
        ((uint4*)outp)[t] = u.q;
    } else {
        cur[threadIdx.x] = 0;
        if (threadIdx.x < 64) hist[threadIdx.x] = 0;
        for (int i = threadIdx.x; i < GMK_CELLS * 16; i += 256)
            gmk[i] = 0u;   // key 0 == -inf sentinel
    }
}

// ---------- MFMA GEMM body: [M,128] @ [128,128] -> fp16 (global A) ----------
// A-frag: A[m=lane&15][k=(lane>>4)*8+j]; C/D: col=lane&15, row=(lane>>4)*4+reg.
__device__ __forceinline__
void gemm_body_f32(int blk, const float* __restrict__ A, const __half* __restrict__ Wz,
                   __half* __restrict__ Out, int n) {
    int wave = threadIdx.x >> 6;
    int lane = threadIdx.x & 63;
    int m0 = blk * 64 + wave * 16;
    if (m0 >= n) return;
    int m = lane & 15;
    int quad = lane >> 4;

    half8 a[4];
#pragma unroll
    for (int kc = 0; kc < 4; kc++) {
        const float* p = &A[(size_t)(m0 + m) * 128 + kc * 32 + quad * 8];
        float4 f0 = *(const float4*)p;
        float4 f1 = *(const float4*)(p + 4);
        UQH8 u;
        u.e[0] = (_Float16)f0.x; u.e[1] = (_Float16)f0.y;
        u.e[2] = (_Float16)f0.z; u.e[3] = (_Float16)f0.w;
        u.e[4] = (_Float16)f1.x; u.e[5] = (_Float16)f1.y;
        u.e[6] = (_Float16)f1.z; u.e[7] = (_Float16)f1.w;
        a[kc] = u.h;
    }

    floatx4 acc[8];
#pragma unroll
    for (int nt = 0; nt < 8; nt++) acc[nt] = (floatx4){0.f, 0.f, 0.f, 0.f};

    const uint4* Wv = (const uint4*)Wz;
#pragma unroll
    for (int kc = 0; kc < 4; kc++) {
#pragma unroll
        for (int nt = 0; nt < 8; nt++) {
            UQH8 u;
            u.q = Wv[(nt * 4 + kc) * 64 + lane];
            acc[nt] = __builtin_amdgcn_mfma_f32_16x16x32_f16(a[kc], u.h, acc[nt], 0, 0, 0);
        }
    }
#pragma unroll
    for (int nt = 0; nt < 8; nt++) {
#pragma unroll
        for (int reg = 0; reg < 4; reg++) {
            Out[(size_t)(m0 + quad * 4 + reg) * 128 + nt * 16 + m] =
                __float2half(acc[nt][reg]);
        }
    }
}

// ---------- coarse scatter via LDS counting sort (blocks < CS_BLOCKS) + GEMM1 ----------
// Stage the chunk in LDS, sort by bucket, reserve one run per bucket with a
// single global atomic, write each run contiguously (avg 128-B bursts,
// amplification ~1 vs random 8-B scatter's partial-line RMW).
// item: .x = (dstLocal<<17) | src  (9+17 bits), .y = bit-cast ew
__launch_bounds__(256)
__global__ void k_csc_gemm(const int* __restrict__ src, const int* __restrict__ dst,
                           const float* __restrict__ ew, int* __restrict__ cur,
                           int2* __restrict__ coarseBuf, int e,
                           const float* __restrict__ x, const __half* __restrict__ w1z,
                           __half* __restrict__ buf0, int n) {
    __shared__ int2 sbuf[SBUF_CAP];
    __shared__ unsigned short sbufb[SBUF_CAP];
    __shared__ int lcnt[256], lofs[256], lpos[256], lbase[256];
    if ((int)blockIdx.x < CS_BLOCKS) {
        int tid = threadIdx.x;
        int chunk = (e + CS_BLOCKS - 1) / CS_BLOCKS;
        int s0 = blockIdx.x * chunk;
        int s1 = min(s0 + chunk, e);
        for (int t0 = s0; t0 < s1; t0 += SBUF_CAP) {
            int t1 = min(t0 + SBUF_CAP, s1);
            lcnt[tid] = 0; lpos[tid] = 0;
            __syncthreads();
            // pass 1: bucket histogram
            for (int i = t0 + tid; i < t1; i += 256)
                atomicAdd(&lcnt[dst[i] >> CB_SHIFT], 1);
            __syncthreads();
            // inclusive Hillis-Steele scan of lcnt -> lofs
            lofs[tid] = lcnt[tid];
            __syncthreads();
            for (int d = 1; d < 256; d <<= 1) {
                int v = (tid >= d) ? lofs[tid - d] : 0;
                __syncthreads();
                lofs[tid] += v;
                __syncthreads();
            }
            // reserve global runs (one atomic per non-empty bucket)
            if (lcnt[tid] > 0) lbase[tid] = atomicAdd(&cur[tid], lcnt[tid]);
            __syncthreads();
            // pass 2: place items into LDS, bucket-sorted
            for (int i = t0 + tid; i < t1; i += 256) {
                int d = dst[i];
                int b = d >> CB_SHIFT;
                int p = (lofs[b] - lcnt[b]) + atomicAdd(&lpos[b], 1);
                sbuf[p] = make_int2(((d & (CB_SIZE - 1)) << 17) | src[i],
                                    __float_as_int(ew[i]));
                sbufb[p] = (unsigned short)b;
            }
            __syncthreads();
            // pass 3: contiguous run write-out (coalesced within runs)
            int total = t1 - t0;
            for (int t = tid; t < total; t += 256) {
                int b = sbufb[t];
                int local = t - (lofs[b] - lcnt[b]);
                int gpos = lbase[b] + local;
                if (gpos < CAP_B)
                    coarseBuf[(size_t)b * CAP_B + gpos] = sbuf[t];
            }
            __syncthreads();
        }
    } else {
        gemm_body_f32(blockIdx.x - CS_BLOCKS, x, w1z, buf0, n);
    }
}

// ---------- fine fill: one 512-thread block per bucket (+ degree histogram) ----------
__launch_bounds__(512)
__global__ void k_fine(const int2* __restrict__ coarseBuf, const int* __restrict__ cur,
                       int2* __restrict__ slots, int* __restrict__ cnt,
                       float* __restrict__ dinv, int* __restrict__ hist, int n) {
    __shared__ int lcnt[CB_SIZE];
    __shared__ float lsum[CB_SIZE];
    __shared__ int lhist[NBINS];
    int b = blockIdx.x;
    int tid = threadIdx.x;
    if (tid < CB_SIZE) { lcnt[tid] = 0; lsum[tid] = 0.f; }
    if (tid < NBINS) lhist[tid] = 0;
    __syncthreads();
    int ecnt = min(cur[b], CAP_B);
    size_t e0 = (size_t)b * CAP_B;
    for (int e = tid; e < ecnt; e += 512) {
        int2 it = coarseBuf[e0 + e];
        int dl = (it.x >> 17) & (CB_SIZE - 1);
        int srcn = it.x & 0x1FFFF;
        int pos = atomicAdd(&lcnt[dl], 1);
        atomicAdd(&lsum[dl], __int_as_float(it.y));
        if (pos < SLOT_CAP) {
            int node = (b << CB_SHIFT) + dl;
            slots[(size_t)node * SLOT_CAP + pos] = make_int2(srcn, it.y);
        }
    }
    __syncthreads();
    if (tid < CB_SIZE) {
        int node = (b << CB_SHIFT) + tid;
        if (node < n) {
            int c = min(lcnt[tid], SLOT_CAP);
            cnt[node] = c;
            dinv[node] = rsqrtf(1.0f + lsum[tid]);
            atomicAdd(&lhist[c], 1);
        }
    }
    __syncthreads();
    if (tid < NBINS && lhist[tid] > 0) atomicAdd(&hist[tid], lhist[tid]);
}

// ---------- degree-bin prefix sum (1 block) ----------
__global__ void k_prefix(const int* __restrict__ hist, int* __restrict__ binCur) {
    if (threadIdx.x == 0) {
        int acc = 0;
        for (int c = 0; c < NBINS; c++) { binCur[c] = acc; acc += hist[c]; }
    }
}

// ---------- permutation scatter: perm sorted by degree (counting sort) ----------
// Equal-degree blocks of 16 reduce divergent-trip-count waste in the gather
// kernels (wave cost = max degree over its node groups).
__launch_bounds__(512)
__global__ void k_permscatter(const int* __restrict__ cnt, int* __restrict__ binCur,
                              int* __restrict__ perm, int n) {
    __shared__ int lh[NBINS], lb[NBINS], lp[NBINS];
    int tid = threadIdx.x;
    if (tid < NBINS) { lh[tid] = 0; lp[tid] = 0; }
    __syncthreads();
    int node = blockIdx.x * 512 + tid;
    int c = -1;
    if (node < n) { c = cnt[node]; atomicAdd(&lh[c], 1); }
    __syncthreads();
    if (tid < NBINS && lh[tid] > 0) lb[tid] = atomicAdd(&binCur[tid], lh[tid]);
    __syncthreads();
    if (node < n) {
        int pos = lb[c] + atomicAdd(&lp[c], 1);
        perm[pos] = node;
    }
}

// ---------- GCN gather body: 16 lanes/node, inline weight dinv[s]*ew*dd ----------
__device__ __forceinline__
void gather_body(int node, int lane, const int* __restrict__ cnt,
                 const int2* __restrict__ slots, const uint4* __restrict__ tv,
                 const float* __restrict__ dinv, const float* __restrict__ b,
                 float* __restrict__ fout) {
    float dd = dinv[node];
    float sw = dd * dd;
    float acc[8];
    {
        uint4 q = tv[(size_t)node * 16 + lane];
        float f[8]; h8f(q, f);
#pragma unroll
        for (int j = 0; j < 8; j++) acc[j] = f[j] * sw;
    }
    int r0 = (int)((size_t)node * SLOT_CAP);
    int r1 = r0 + cnt[node];
    int e = r0;
    for (; e + 8 <= r1; e += 8) {
        int2 c[8];
        float dv[8];
        uint4 v[8];
#pragma unroll
        for (int j = 0; j < 8; j++) c[j] = slots[e + j];
#pragma unroll
        for (int j = 0; j < 8; j++) dv[j] = dinv[c[j].x];
#pragma unroll
        for (int j = 0; j < 8; j++) v[j] = tv[(size_t)c[j].x * 16 + lane];
#pragma unroll
        for (int j = 0; j < 8; j++) {
            float w = dv[j] * __int_as_float(c[j].y) * dd;
            float f[8]; h8f(v[j], f);
#pragma unroll
            for (int k = 0; k < 8; k++) acc[k] = fmaf(f[k], w, acc[k]);
        }
    }
    for (; e + 2 <= r1; e += 2) {
        int2 c0 = slots[e], c1 = slots[e + 1];
        float dv0 = dinv[c0.x], dv1 = dinv[c1.x];
        uint4 v0 = tv[(size_t)c0.x * 16 + lane];
        uint4 v1 = tv[(size_t)c1.x * 16 + lane];
        float w0 = dv0 * __int_as_float(c0.y) * dd;
        float w1 = dv1 * __int_as_float(c1.y) * dd;
        float f0[8], f1[8]; h8f(v0, f0); h8f(v1, f1);
#pragma unroll
        for (int k = 0; k < 8; k++) acc[k] = fmaf(f0[k], w0, acc[k]);
#pragma unroll
        for (int k = 0; k < 8; k++) acc[k] = fmaf(f1[k], w1, acc[k]);
    }
    if (e < r1) {
        int2 c = slots[e];
        uint4 v = tv[(size_t)c.x * 16 + lane];
        float w = dinv[c.x] * __int_as_float(c.y) * dd;
        float f[8]; h8f(v, f);
#pragma unroll
        for (int k = 0; k < 8; k++) acc[k] = fmaf(f[k], w, acc[k]);
    }
    const float4* b4 = (const float4*)b;
    float4 bb0 = b4[lane * 2], bb1 = b4[lane * 2 + 1];
    fout[0] = fmaxf(acc[0] + bb0.x, 0.f);
    fout[1] = fmaxf(acc[1] + bb0.y, 0.f);
    fout[2] = fmaxf(acc[2] + bb0.z, 0.f);
    fout[3] = fmaxf(acc[3] + bb0.w, 0.f);
    fout[4] = fmaxf(acc[4] + bb1.x, 0.f);
    fout[5] = fmaxf(acc[5] + bb1.y, 0.f);
    fout[6] = fmaxf(acc[6] + bb1.z, 0.f);
    fout[7] = fmaxf(acc[7] + bb1.w, 0.f);
}

// ---------- fused GCN gather + MFMA GEMM (+ optional attn epilogue) ----------
// Block = 16 PERMUTED nodes (degree-sorted: near-equal trip counts per wave).
// Phase 1: gather h into LDS stage. Phase 2: MFMA; outputs written through perm.
template <bool ATTN>
__launch_bounds__(256)
__global__ void k_gather_gemm(const int* __restrict__ cnt, const int2* __restrict__ slots,
                              const __half* __restrict__ t, const float* __restrict__ dinv,
                              const float* __restrict__ b, const __half* __restrict__ Wz,
                              __half* __restrict__ Out, const int* __restrict__ perm,
                              const float* __restrict__ attS, const float* __restrict__ attD,
                              float* __restrict__ as_, float* __restrict__ ad_,
                              unsigned* __restrict__ gmaxKey, int n) {
    __shared__ __half stage[16][136];      // 272-B row stride: <=2-way LDS aliasing
    __shared__ float redS[4][16], redD[4][16];
    int tid = threadIdx.x;
    int nl = tid >> 4;
    int lane16 = tid & 15;
    int idx16 = blockIdx.x * 16 + nl;
    int node = (idx16 < n) ? perm[idx16] : -1;

    if (node >= 0) {
        float f[8];
        gather_body(node, lane16, cnt, slots, (const uint4*)t, dinv, b, f);
        UQH8 u;
#pragma unroll
        for (int j = 0; j < 8; j++) u.e[j] = (_Float16)f[j];
        *(uint4*)&stage[nl][lane16 * 8] = u.q;
    } else {
        UQH8 u;
#pragma unroll
        for (int j = 0; j < 8; j++) u.e[j] = (_Float16)0.f;
        *(uint4*)&stage[nl][lane16 * 8] = u.q;
    }
    __syncthreads();

    int wave = tid >> 6;
    int lane = tid & 63;
    int m = lane & 15;
    int quad = lane >> 4;
    int m0 = blockIdx.x * 16;

    half8 a[4];
#pragma unroll
    for (int kc = 0; kc < 4; kc++)
        a[kc] = *(const half8*)&stage[m][kc * 32 + quad * 8];

    floatx4 acc[2];
    acc[0] = (floatx4){0.f, 0.f, 0.f, 0.f};
    acc[1] = (floatx4){0.f, 0.f, 0.f, 0.f};
    const uint4* Wv = (const uint4*)Wz;
#pragma unroll
    for (int t2 = 0; t2 < 2; t2++) {
        int nt = wave * 2 + t2;
#pragma unroll
        for (int kc = 0; kc < 4; kc++) {
            UQH8 u;
            u.q = Wv[(nt * 4 + kc) * 64 + lane];
            acc[t2] = __builtin_amdgcn_mfma_f32_16x16x32_f16(a[kc], u.h, acc[t2], 0, 0, 0);
        }
    }
#pragma unroll
    for (int reg = 0; reg < 4; reg++) {
        int row = m0 + quad * 4 + reg;
        if (row < n) {
            int prow = perm[row];
#pragma unroll
            for (int t2 = 0; t2 < 2; t2++) {
                int col = (wave * 2 + t2) * 16 + m;
                Out[(size_t)prow * 128 + col] = __float2half(acc[t2][reg]);
            }
        }
    }

    if (ATTN) {
        float sv0 = attS[(wave * 2 + 0) * 16 + m], sv1 = attS[(wave * 2 + 1) * 16 + m];
        float dv0 = attD[(wave * 2 + 0) * 16 + m], dv1 = attD[(wave * 2 + 1) * 16 + m];
#pragma unroll
        for (int reg = 0; reg < 4; reg++) {
            float s = acc[0][reg] * sv0 + acc[1][reg] * sv1;
            float d = acc[0][reg] * dv0 + acc[1][reg] * dv1;
#pragma unroll
            for (int k = 8; k >= 1; k >>= 1) {
                s += __shfl_xor(s, k, 64);   // xor bits <16: stays in quad's 16-group
                d += __shfl_xor(d, k, 64);
            }
            if (m == 0) {
                redS[wave][quad * 4 + reg] = s;
                redD[wave][quad * 4 + reg] = d;
            }
        }
        __syncthreads();
        if (tid < 16) {
            int nd = m0 + tid;
            unsigned key = 0u;
            if (nd < n) {
                float sv = redS[0][tid] + redS[1][tid] + redS[2][tid] + redS[3][tid];
                float dv = redD[0][tid] + redD[1][tid] + redD[2][tid] + redD[3][tid];
                int pn = perm[nd];
                as_[pn] = sv;
                ad_[pn] = dv;
                key = fkey(sv);
            }
            // max of the 16 keys (xor bits <16 keep lanes 0..15 within group)
#pragma unroll
            for (int k = 8; k >= 1; k >>= 1) {
                unsigned o = (unsigned)__shfl_xor((int)key, k, 64);
                key = key > o ? key : o;
            }
            if (tid == 0)
                atomicMax(&gmaxKey[(blockIdx.x & (GMK_CELLS - 1)) << 4], key);
        }
    }
}

// ---------- GAT gather + fused final projection (perm-ordered blocks) ----------
// Edge softmax uses a per-node shift c = lrelu(gmax_as + ad[node]) which upper
// bounds every logit of the node (lrelu is monotone). Softmax is invariant to
// the shift, so no segment-max pass is needed; exp args stay in [-~10, 0].
__launch_bounds__(256)
__global__ void k_gat_final(const int* __restrict__ cnt, const int2* __restrict__ slots,
                            const __half* __restrict__ g, const float* __restrict__ as_,
                            const float* __restrict__ ad_,
                            const unsigned* __restrict__ gmaxKey,
                            const int* __restrict__ perm,
                            const float* __restrict__ bg,
                            const float* __restrict__ Wc, const float* __restrict__ bc,
                            float* __restrict__ out, int n) {
    __shared__ float Wcs[128 * 16];
    __shared__ float bcs[16];
    __shared__ float stage[16][136];
    __shared__ float gmaxS;
    int tid = threadIdx.x;
    for (int i = tid; i < 128 * 16; i += 256) Wcs[i] = Wc[i];
    if (tid < 16) bcs[tid] = bc[tid];

    // reduce the 64 spread max-cells (first wave), broadcast via LDS
    if (tid < 64) {
        unsigned k = gmaxKey[tid << 4];
#pragma unroll
        for (int d = 32; d >= 1; d >>= 1) {
            unsigned o = (unsigned)__shfl_xor((int)k, d, 64);
            k = k > o ? k : o;
        }
        if (tid == 0) gmaxS = funkey(k);
    }
    __syncthreads();
    float gmax = gmaxS;

    int idx = blockIdx.x * 256 + tid;
    int lidx = idx >> 4;
    int node = (lidx < n) ? perm[lidx] : -1;
    int lane = idx & 15;
    int nl = tid >> 4;

    if (node >= 0) {
        int r0 = (int)((size_t)node * SLOT_CAP);
        int r1 = r0 + cnt[node];
        float ad_d = ad_[node];
        float c = lrelu02(gmax + ad_d);          // upper bound of all logits
        const uint4* gv = (const uint4*)g;
        float ex = __expf(lrelu02(as_[node] + ad_d) - c);
        float den = ex;
        float acc[8];
        {
            uint4 q = gv[(size_t)node * 16 + lane];
            float f[8]; h8f(q, f);
#pragma unroll
            for (int j = 0; j < 8; j++) acc[j] = ex * f[j];
        }
        int e = r0;
        for (; e + 8 <= r1; e += 8) {
            int s[8];
            float av[8];
            uint4 u[8];
#pragma unroll
            for (int j = 0; j < 8; j++) s[j] = slots[e + j].x;
#pragma unroll
            for (int j = 0; j < 8; j++) av[j] = as_[s[j]];
#pragma unroll
            for (int j = 0; j < 8; j++) u[j] = gv[(size_t)s[j] * 16 + lane];
#pragma unroll
            for (int j = 0; j < 8; j++) {
                float w = __expf(lrelu02(av[j] + ad_d) - c);
                den += w;
                float f[8]; h8f(u[j], f);
#pragma unroll
                for (int k = 0; k < 8; k++) acc[k] = fmaf(f[k], w, acc[k]);
            }
        }
        for (; e + 2 <= r1; e += 2) {
            int s0 = slots[e].x, s1 = slots[e + 1].x;
            uint4 u0 = gv[(size_t)s0 * 16 + lane];
            uint4 u1 = gv[(size_t)s1 * 16 + lane];
            float w0 = __expf(lrelu02(as_[s0] + ad_d) - c);
            float w1 = __expf(lrelu02(as_[s1] + ad_d) - c);
            den += w0 + w1;
            float f0[8], f1[8]; h8f(u0, f0); h8f(u1, f1);
#pragma unroll
            for (int k = 0; k < 8; k++) acc[k] = fmaf(f0[k], w0, acc[k]);
#pragma unroll
            for (int k = 0; k < 8; k++) acc[k] = fmaf(f1[k], w1, acc[k]);
        }
        if (e < r1) {
            int s = slots[e].x;
            uint4 u = gv[(size_t)s * 16 + lane];
            float w = __expf(lrelu02(as_[s] + ad_d) - c);
            den += w;
            float f[8]; h8f(u, f);
#pragma unroll
            for (int k = 0; k < 8; k++) acc[k] = fmaf(f[k], w, acc[k]);
        }
        float inv = 1.0f / den;
        const float4* bg4 = (const float4*)bg;
        float4 b0 = bg4[lane * 2], b1 = bg4[lane * 2 + 1];
        float* sp = &stage[nl][lane * 8];
        sp[0] = fmaxf(acc[0] * inv + b0.x, 0.f);
        sp[1] = fmaxf(acc[1] * inv + b0.y, 0.f);
        sp[2] = fmaxf(acc[2] * inv + b0.z, 0.f);
        sp[3] = fmaxf(acc[3] * inv + b0.w, 0.f);
        sp[4] = fmaxf(acc[4] * inv + b1.x, 0.f);
        sp[5] = fmaxf(acc[5] * inv + b1.y, 0.f);
        sp[6] = fmaxf(acc[6] * inv + b1.z, 0.f);
        sp[7] = fmaxf(acc[7] * inv + b1.w, 0.f);
    }
    __syncthreads();
    int nl2 = tid >> 4;
    int col = tid & 15;
    int oidx = blockIdx.x * 16 + nl2;
    if (oidx >= n) return;
    int onode = perm[oidx];
    float accp = bcs[col];
    const float* sp = stage[nl2];
#pragma unroll 8
    for (int k = 0; k < 128; k++)
        accp = fmaf(sp[k], Wcs[k * 16 + col], accp);
    out[(size_t)onode * 16 + col] = accp;
}

// ---------- launch ----------
extern "C" void kernel_launch(void* const* d_in, const int* in_sizes, int n_in,
                              void* d_out, int out_size, void* d_ws, size_t ws_size,
                              hipStream_t stream) {
    const float* x      = (const float*)d_in[0];
    const int*   eidx   = (const int*)d_in[1];
    const float* ew     = (const float*)d_in[2];
    const float* W1     = (const float*)d_in[3];
    const float* b1     = (const float*)d_in[4];
    const float* W2     = (const float*)d_in[5];
    const float* b2     = (const float*)d_in[6];
    const float* Wg     = (const float*)d_in[7];
    const float* attS   = (const float*)d_in[8];
    const float* attD   = (const float*)d_in[9];
    const float* bg     = (const float*)d_in[10];
    const float* Wc     = (const float*)d_in[11];
    const float* bc     = (const float*)d_in[12];

    const int N = in_sizes[0] / FIN;   // 100000
    const int E = in_sizes[2];         // 1600000
    const int* src = eidx;
    const int* dst = eidx + E;
    const int NB = (N + CB_SIZE - 1) >> CB_SHIFT;   // 196 buckets (<= 256)

    // 256-B aligned workspace carve (16-B misalignment = +50% gather traffic).
    char* base = (char*)d_ws;
    size_t off = 0;
    auto carve = [&](size_t bytes) {
        char* q = base + off;
        off = (off + bytes + 255) & ~(size_t)255;
        return (void*)q;
    };
    int*    cnt       = (int*)carve((size_t)N * 4);
    int*    cur       = (int*)carve(256 * 4);
    unsigned* gmk     = (unsigned*)carve((size_t)GMK_CELLS * 16 * 4);
    int*    hist      = (int*)carve(64 * 4);
    int*    binCur    = (int*)carve(64 * 4);
    int*    perm      = (int*)carve((size_t)N * 4);
    int2*   coarseBuf = (int2*)carve((size_t)NB * CAP_B * 8);
    int2*   slots     = (int2*)carve((size_t)N * SLOT_CAP * 8);
    float*  dinv      = (float*)carve((size_t)N * 4);
    float*  as_       = (float*)carve((size_t)N * 4);
    float*  ad_       = (float*)carve((size_t)N * 4);
    __half* w1z       = (__half*)carve((size_t)128 * 128 * 2);
    __half* w2z       = (__half*)carve((size_t)128 * 128 * 2);
    __half* wgz       = (__half*)carve((size_t)128 * 128 * 2);
    __half* buf0      = (__half*)carve((size_t)N * 128 * 2);
    __half* buf1      = (__half*)carve((size_t)N * 128 * 2);

    const int B = 256;
    dim3 blk(B);
    int fusedGrid = (N + 15) / 16;       // 16 nodes per block
    int gemmGrid = (N + 63) / 64;

    k_setup<<<25, blk, 0, stream>>>(W1, W2, Wg, w1z, w2z, wgz, cur, gmk, hist);
    k_csc_gemm<<<CS_BLOCKS + gemmGrid, blk, 0, stream>>>(src, dst, ew, cur, coarseBuf, E,
                                                         x, w1z, buf0, N);
    k_fine<<<NB, dim3(512), 0, stream>>>(coarseBuf, cur, slots, cnt, dinv, hist, N);
    k_prefix<<<1, dim3(64), 0, stream>>>(hist, binCur);
    k_permscatter<<<NB, dim3(512), 0, stream>>>(cnt, binCur, perm, N);

    k_gather_gemm<false><<<fusedGrid, blk, 0, stream>>>(cnt, slots, buf0, dinv, b1, w2z,
                                                        buf1, perm, nullptr, nullptr,
                                                        nullptr, nullptr, nullptr, N);
    k_gather_gemm<true><<<fusedGrid, blk, 0, stream>>>(cnt, slots, buf1, dinv, b2, wgz,
                                                       buf0, perm, attS, attD, as_, ad_,
                                                       gmk, N);
    k_gat_final<<<fusedGrid, blk, 0, stream>>>(cnt, slots, buf0, as_, ad_, gmk, perm, bg,
                                               Wc, bc, (float*)d_out, N);
}